// Round 3
// baseline (479.373 us; speedup 1.0000x reference)
//
#include <hip/hip_runtime.h>
#include <cmath>

#define SLEN 2048

typedef __bf16 bf16x8 __attribute__((ext_vector_type(8)));
typedef float  f32x4  __attribute__((ext_vector_type(4)));

__device__ inline void gld16(const void* g, void* l) {
    __builtin_amdgcn_global_load_lds(
        (const __attribute__((address_space(1))) void*)(uintptr_t)g,
        (__attribute__((address_space(3))) void*)(unsigned)(uintptr_t)l, 16, 0, 0);
}

// ---------------------------------------------------------------------------
// One-launch fp32->bf16 convert of all 9 inputs (segment table by value).
// ---------------------------------------------------------------------------
struct CvArgs {
    const float* src[9];
    __bf16*      dst[9];
    long         cum[10];
};
__global__ __launch_bounds__(256)
void convert_all(CvArgs a) {
    long i8 = ((long)blockIdx.x * 256 + threadIdx.x) * 8;
    if (i8 >= a.cum[9]) return;
    int s = 0;
#pragma unroll
    for (int k = 1; k < 9; k++) if (i8 >= a.cum[k]) s = k;
    long loc = i8 - a.cum[s];
    const float* sp = a.src[s] + loc;
    float4 u0 = *(const float4*)(sp);
    float4 u1 = *(const float4*)(sp + 4);
    bf16x8 o;
    o[0] = (__bf16)u0.x; o[1] = (__bf16)u0.y; o[2] = (__bf16)u0.z; o[3] = (__bf16)u0.w;
    o[4] = (__bf16)u1.x; o[5] = (__bf16)u1.y; o[6] = (__bf16)u1.z; o[7] = (__bf16)u1.w;
    *(bf16x8*)(a.dst[s] + loc) = o;
}

struct Outs { __bf16* a; __bf16* b; __bf16* c; float* f; };

// ---------------------------------------------------------------------------
// Old NT GEMM, 128x128x64 tiles, 4 waves.  Now used ONLY for the k-rope strip
// of gemm1 (n_off=2048, one column tile, mode 8 rope+broadcast epilogue).
// ---------------------------------------------------------------------------
__global__ __launch_bounds__(256, 2)
void gemm_nt(const __bf16* __restrict__ A, const __bf16* __restrict__ B,
             Outs o, const int* __restrict__ positions,
             int M, int N, int K, int mode, float scale, int n_off) {
    __shared__ __bf16 As[128 * 64];
    __shared__ __bf16 Bs[128 * 64];
    int tid = threadIdx.x;
    int wave = tid >> 6, lane = tid & 63;
    int lane15 = lane & 15, quad = lane >> 4;
    int ri = lane >> 3, ci = lane & 7;
    int cg = ci ^ ri;
    int m0 = blockIdx.x * 128, n0 = blockIdx.y * 128 + n_off;
    int wm = (wave & 1) * 64, wn = (wave >> 1) * 64;
    f32x4 acc[4][4] = {};

    for (int k0 = 0; k0 < K; k0 += 64) {
#pragma unroll
        for (int t = 0; t < 4; t++) {
            int rr = wave * 32 + t * 8;
            int r = rr + ri;
            gld16(A + (size_t)(m0 + r) * K + k0 + cg * 8, As + rr * 64);
            int br = n0 + r; if (br > N - 1) br = N - 1;
            gld16(B + (size_t)br * K + k0 + cg * 8, Bs + rr * 64);
        }
        __syncthreads();
#pragma unroll
        for (int kk = 0; kk < 64; kk += 32) {
            int jb = kk >> 3;
            bf16x8 af[4], bfr[4];
#pragma unroll
            for (int mt = 0; mt < 4; mt++) {
                int rA = wm + mt * 16 + lane15;
                af[mt] = *(bf16x8*)(As + rA * 64 + (((jb + quad) ^ (rA & 7)) << 3));
            }
#pragma unroll
            for (int nt = 0; nt < 4; nt++) {
                int rB = wn + nt * 16 + lane15;
                bfr[nt] = *(bf16x8*)(Bs + rB * 64 + (((jb + quad) ^ (rB & 7)) << 3));
            }
#pragma unroll
            for (int mt = 0; mt < 4; mt++)
#pragma unroll
                for (int nt = 0; nt < 4; nt++)
                    acc[mt][nt] = __builtin_amdgcn_mfma_f32_16x16x32_bf16(
                        af[mt], bfr[nt], acc[mt][nt], 0, 0, 0);
        }
        __syncthreads();
    }

    const float KLOG = 13.287712379549449f / 32.0f;  // log2(10000)/32

    if (mode == 8 && n0 == 2048) {                     // k-rope + broadcast
        if (wn == 0) {
#pragma unroll
            for (int mt = 0; mt < 4; mt++) {
                int row = m0 + wm + mt * 16 + quad * 4;
#pragma unroll
                for (int nt = 0; nt < 2; nt++) {
                    int i = nt * 16 + lane15;          // 0..31
                    float inv = exp2f(-(float)i * KLOG);
#pragma unroll
                    for (int r = 0; r < 4; r++) {
                        int tok = row + r;
                        float p = (float)positions[tok & (SLEN - 1)];
                        float sn, cs; sincosf(p * inv, &sn, &cs);
                        float t1 = acc[mt][nt][r], t2 = acc[mt][nt + 2][r];
                        float rot1 = t1 * cs - t2 * sn;
                        float rot2 = t2 * cs + t1 * sn;
                        size_t ob = (size_t)tok * 3072 + 128;
#pragma unroll
                        for (int hh = 0; hh < 16; hh++) {
                            o.c[ob + hh * 192 + i]      = (__bf16)rot1;
                            o.c[ob + hh * 192 + 32 + i] = (__bf16)rot2;
                        }
                    }
                }
            }
        }
        return;
    }
}

// ---------------------------------------------------------------------------
// New NT GEMM: 256x128x64 tiles, 8 waves (4 row x 2 col, each 64x64 out),
// double-buffered LDS (96 KiB -> 1 block/CU), phase-split K-step:
//   phase0: issue 3 next-tile gld16 | ds_read kk=0 frags | 16 MFMA | s_barrier
//   phase1: issue 3 next-tile gld16 | ds_read kk=1 frags | 16 MFMA | syncthreads
// Next-tile loads get ~a full phase+ of MFMA/ds_read cover before the
// end-of-tile drain.  s_setprio(1) around MFMA clusters (T5).
// 1D grid, bijective XCD remap (m204): each XCD owns contiguous col-tiles ->
// B (weight) panels stay L2-resident per XCD.
// Epilogue modes as before: 2 fp32-out, 8 c_q|c_kv split, 9 q_all(+rope),
// 10 k_all | v_t transpose.
// ---------------------------------------------------------------------------
__global__ __launch_bounds__(512, 2)
void gemm_nt2(const __bf16* __restrict__ A, const __bf16* __restrict__ B,
              Outs o, const int* __restrict__ positions,
              int N, int K, int mode, float scale) {
    __shared__ __bf16 As[2][256 * 64];
    __shared__ __bf16 Bs[2][128 * 64];
    int tid = threadIdx.x;
    int wave = tid >> 6, lane = tid & 63;
    int lane15 = lane & 15, quad = lane >> 4;
    int wr = wave >> 1, wc = wave & 1;
    int lr = lane >> 3, lc = lane & 7;

    int nblk = gridDim.x;
    int qq = nblk >> 3;                       // nblk % 8 == 0 always
    int bid = blockIdx.x;
    int wg = (bid & 7) * qq + (bid >> 3);     // bijective XCD remap
    int m0 = (wg & 15) * 256;                 // M = 4096 fixed
    int n0 = (wg >> 4) * 128;

    f32x4 acc[4][4] = {};
    int NT = K >> 6;

    auto stageA = [&](int t, int k0, int buf) {
        int rr = t * 64 + wave * 8;
        int r = rr + lr;
        int cg = lc ^ (r & 7);
        gld16(A + (size_t)(m0 + r) * K + k0 + cg * 8, &As[buf][0] + rr * 64);
    };
    auto stageB = [&](int t, int k0, int buf) {
        int rr = t * 64 + wave * 8;
        int r = rr + lr;
        int cg = lc ^ (r & 7);
        int br = n0 + r; if (br > N - 1) br = N - 1;
        gld16(B + (size_t)br * K + k0 + cg * 8, &Bs[buf][0] + rr * 64);
    };

    // prologue: stage tile 0 fully
#pragma unroll
    for (int t = 0; t < 4; t++) stageA(t, 0, 0);
#pragma unroll
    for (int t = 0; t < 2; t++) stageB(t, 0, 0);
    __syncthreads();

    for (int t = 0; t < NT; t++) {
        int cur = t & 1;
        int k1 = (t + 1) << 6;
        bool more = (t + 1) < NT;

        // ---- phase 0 (kk = 0, chunk j = quad) ----
        if (more) { stageA(0, k1, cur ^ 1); stageA(1, k1, cur ^ 1); stageB(0, k1, cur ^ 1); }
        {
            bf16x8 af[4], bfr[4];
#pragma unroll
            for (int mt = 0; mt < 4; mt++) {
                int rA = wr * 64 + mt * 16 + lane15;
                af[mt] = *(bf16x8*)(&As[cur][0] + rA * 64 + ((quad ^ (rA & 7)) << 3));
            }
#pragma unroll
            for (int nt = 0; nt < 4; nt++) {
                int rB = wc * 64 + nt * 16 + lane15;
                bfr[nt] = *(bf16x8*)(&Bs[cur][0] + rB * 64 + ((quad ^ (rB & 7)) << 3));
            }
            __builtin_amdgcn_s_setprio(1);
#pragma unroll
            for (int mt = 0; mt < 4; mt++)
#pragma unroll
                for (int nt = 0; nt < 4; nt++)
                    acc[mt][nt] = __builtin_amdgcn_mfma_f32_16x16x32_bf16(
                        af[mt], bfr[nt], acc[mt][nt], 0, 0, 0);
            __builtin_amdgcn_s_setprio(0);
        }
        __builtin_amdgcn_s_barrier();   // mid-tile scheduling fence

        // ---- phase 1 (kk = 1, chunk j = 4 + quad) ----
        if (more) { stageA(2, k1, cur ^ 1); stageA(3, k1, cur ^ 1); stageB(1, k1, cur ^ 1); }
        {
            bf16x8 af[4], bfr[4];
#pragma unroll
            for (int mt = 0; mt < 4; mt++) {
                int rA = wr * 64 + mt * 16 + lane15;
                af[mt] = *(bf16x8*)(&As[cur][0] + rA * 64 + (((4 + quad) ^ (rA & 7)) << 3));
            }
#pragma unroll
            for (int nt = 0; nt < 4; nt++) {
                int rB = wc * 64 + nt * 16 + lane15;
                bfr[nt] = *(bf16x8*)(&Bs[cur][0] + rB * 64 + (((4 + quad) ^ (rB & 7)) << 3));
            }
            __builtin_amdgcn_s_setprio(1);
#pragma unroll
            for (int mt = 0; mt < 4; mt++)
#pragma unroll
                for (int nt = 0; nt < 4; nt++)
                    acc[mt][nt] = __builtin_amdgcn_mfma_f32_16x16x32_bf16(
                        af[mt], bfr[nt], acc[mt][nt], 0, 0, 0);
            __builtin_amdgcn_s_setprio(0);
        }
        __syncthreads();                // drains vmcnt+lgkm: next tile ready
    }

    const float KLOG = 13.287712379549449f / 32.0f;  // log2(10000)/32

    if (mode == 9 && n0 >= 2048) {                     // q-rope (scaled)
        int hh = (n0 + wc * 64 - 2048) >> 6;
#pragma unroll
        for (int mt = 0; mt < 4; mt++) {
            int row = m0 + wr * 64 + mt * 16 + quad * 4;
#pragma unroll
            for (int nt = 0; nt < 2; nt++) {
                int i = nt * 16 + lane15;              // 0..31
                float inv = exp2f(-(float)i * KLOG);
#pragma unroll
                for (int r = 0; r < 4; r++) {
                    int tok = row + r;
                    float p = (float)positions[tok & (SLEN - 1)];
                    float sn, cs; sincosf(p * inv, &sn, &cs);
                    float t1 = acc[mt][nt][r], t2 = acc[mt][nt + 2][r];
                    size_t ob = (size_t)tok * 3072 + hh * 192 + 128;
                    o.a[ob + i]      = (__bf16)((t1 * cs - t2 * sn) * scale);
                    o.a[ob + 32 + i] = (__bf16)((t2 * cs + t1 * sn) * scale);
                }
            }
        }
        return;
    }

#pragma unroll
    for (int mt = 0; mt < 4; mt++) {
        int row = m0 + wr * 64 + mt * 16 + quad * 4;
#pragma unroll
        for (int nt = 0; nt < 4; nt++) {
            int col = n0 + wc * 64 + nt * 16 + lane15;
#pragma unroll
            for (int r = 0; r < 4; r++) {
                float v = acc[mt][nt][r];
                size_t rw = (size_t)(row + r);
                if (mode == 2) {
                    o.f[rw * N + col] = v;
                } else if (mode == 8) {
                    if (col < 1536) o.a[rw * 1536 + col] = (__bf16)v;
                    else            o.b[rw * 512 + col - 1536] = (__bf16)v;
                } else if (mode == 9) {
                    o.a[rw * 3072 + (col >> 7) * 192 + (col & 127)] =
                        (__bf16)(v * scale);
                } else {  // 10
                    if (col < 2048)
                        o.a[rw * 3072 + (col >> 7) * 192 + (col & 127)] = (__bf16)v;
                    else {
                        int d = col - 2048;
                        o.b[((size_t)d * 2 + (rw >> 11)) * 2048 + (rw & 2047)] = (__bf16)v;
                    }
                }
            }
        }
    }
}

// ---------------------------------------------------------------------------
// Causal flash attention, Q-tile 128 (4 waves x 32 q-rows), K/V-tile 64.
// Reverted to the verified-best v1 structure (complementary (qt,15-qt)
// b-partners -> every CU's co-resident pair totals 17 tile-units), plus
// s_setprio(1) around MFMA clusters (T5; m191's regime: independent blocks
// sharing a CU).
// ---------------------------------------------------------------------------
__global__ __launch_bounds__(256, 2)
void mla_attn(const __bf16* __restrict__ Q, const __bf16* __restrict__ K,
              const __bf16* __restrict__ Vt, __bf16* __restrict__ O) {
    __shared__ __bf16 Ks[64 * 192];
    __shared__ __bf16 Vs[128 * 64];
    __shared__ __bf16 Ps[4][32][72];
    int tid = threadIdx.x, wave = tid >> 6, lane = tid & 63;
    int lane15 = lane & 15, quad = lane >> 4;
    int h = blockIdx.y, b = blockIdx.z;
    int x = blockIdx.x;
    int qt0 = (x & 1) ? (x >> 1) : (15 - (x >> 1));
    int qt = b ? (15 - qt0) : qt0;
    int q0 = qt * 128;
    const __bf16* Qb  = Q + (size_t)b * SLEN * 3072 + h * 192;
    const __bf16* Kb  = K + (size_t)b * SLEN * 3072 + h * 192;
    const __bf16* vtb = Vt + ((size_t)(h * 128) * 2 + b) * 2048;

    bf16x8 qf[2][6];
#pragma unroll
    for (int mt = 0; mt < 2; mt++) {
        int qrow = q0 + wave * 32 + mt * 16 + lane15;
#pragma unroll
        for (int kk = 0; kk < 6; kk++)
            qf[mt][kk] = *(const bf16x8*)(Qb + (size_t)qrow * 3072 + kk * 32 + quad * 8);
    }
    bf16x8 ones;
#pragma unroll
    for (int e = 0; e < 8; e++) ones[e] = (__bf16)1.0f;

    f32x4 o_acc[2][8] = {};
    float m_i[2][4], l_i[2][4];
#pragma unroll
    for (int mt = 0; mt < 2; mt++)
#pragma unroll
        for (int r = 0; r < 4; r++) { m_i[mt][r] = -3.0e38f; l_i[mt][r] = 0.0f; }

    for (int j0 = 0; j0 <= q0 + 64; j0 += 64) {
        // stage K (64x192) and V (128x64), swizzled, via global_load_lds
#pragma unroll
        for (int t = 0; t < 6; t++) {
            int sb = (wave * 6 + t) * 64;
            int slot = sb + lane;
            int r = slot / 24;
            int c = slot - r * 24;
            int cgk = (c & ~7) | ((c & 7) ^ (r & 7));
            gld16(Kb + (size_t)(j0 + r) * 3072 + cgk * 8, Ks + sb * 8);
        }
#pragma unroll
        for (int t = 0; t < 4; t++) {
            int sb = (wave * 4 + t) * 64;
            int slot = sb + lane;
            int r = slot >> 3, c = slot & 7;
            gld16(vtb + (size_t)r * 4096 + j0 + (c ^ (r & 7)) * 8, Vs + sb * 8);
        }
        __syncthreads();

        // QK^T: 2 m-tiles x 4 n-tiles
        f32x4 acc[2][4] = {};
        __builtin_amdgcn_s_setprio(1);
#pragma unroll
        for (int kk = 0; kk < 6; kk++) {
#pragma unroll
            for (int nt = 0; nt < 4; nt++) {
                int n = nt * 16 + lane15;
                int j = kk * 4 + quad;
                int cl = (j & ~7) | ((j & 7) ^ (n & 7));
                bf16x8 kf = *(bf16x8*)(Ks + n * 192 + cl * 8);
#pragma unroll
                for (int mt = 0; mt < 2; mt++)
                    acc[mt][nt] = __builtin_amdgcn_mfma_f32_16x16x32_bf16(
                        qf[mt][kk], kf, acc[mt][nt], 0, 0, 0);
            }
        }
        __builtin_amdgcn_s_setprio(0);

        if (j0 >= q0) {  // causal mask (only last two tiles)
#pragma unroll
            for (int mt = 0; mt < 2; mt++) {
                int rowg = q0 + wave * 32 + mt * 16 + quad * 4;
#pragma unroll
                for (int nt = 0; nt < 4; nt++) {
                    int colg = j0 + nt * 16 + lane15;
#pragma unroll
                    for (int r = 0; r < 4; r++)
                        if (colg > rowg + r) acc[mt][nt][r] = -3.0e38f;
                }
            }
        }

        // threshold-max: slow path only when tile max exceeds m+24
        float mx[2][4];
        bool need = false;
#pragma unroll
        for (int mt = 0; mt < 2; mt++)
#pragma unroll
            for (int r = 0; r < 4; r++) {
                float v = fmaxf(fmaxf(acc[mt][0][r], acc[mt][1][r]),
                                fmaxf(acc[mt][2][r], acc[mt][3][r]));
                mx[mt][r] = v;
                need = need || (v > m_i[mt][r] + 24.0f);
            }
        if (__any(need)) {
#pragma unroll
            for (int mt = 0; mt < 2; mt++)
#pragma unroll
                for (int r = 0; r < 4; r++) {
                    float v = mx[mt][r];
#pragma unroll
                    for (int d = 8; d >= 1; d >>= 1) v = fmaxf(v, __shfl_xor(v, d));
                    float mn = fmaxf(m_i[mt][r], v);
                    float alpha = exp2f(m_i[mt][r] - mn);
                    m_i[mt][r] = mn;
                    l_i[mt][r] *= alpha;
#pragma unroll
                    for (int nt = 0; nt < 8; nt++) o_acc[mt][nt][r] *= alpha;
                }
        }

        // P = exp2(acc - m), store to Ps (A-layout round-trip)
#pragma unroll
        for (int mt = 0; mt < 2; mt++)
#pragma unroll
            for (int r = 0; r < 4; r++)
#pragma unroll
                for (int nt = 0; nt < 4; nt++) {
                    float pp = exp2f(acc[mt][nt][r] - m_i[mt][r]);
                    Ps[wave][mt * 16 + quad * 4 + r][nt * 16 + lane15] = (__bf16)pp;
                }

        // PV + row-sum MFMA
        f32x4 rs[2] = {};
        __builtin_amdgcn_s_setprio(1);
#pragma unroll
        for (int ks = 0; ks < 2; ks++) {
            bf16x8 pf[2];
#pragma unroll
            for (int mt = 0; mt < 2; mt++)
                pf[mt] = *(bf16x8*)(&Ps[wave][mt * 16 + lane15][ks * 32 + quad * 8]);
#pragma unroll
            for (int nt = 0; nt < 8; nt++) {
                int nn = nt * 16 + lane15;
                int j = ks * 4 + quad;
                bf16x8 vf = *(bf16x8*)(Vs + nn * 64 + (j ^ (nn & 7)) * 8);
#pragma unroll
                for (int mt = 0; mt < 2; mt++)
                    o_acc[mt][nt] = __builtin_amdgcn_mfma_f32_16x16x32_bf16(
                        pf[mt], vf, o_acc[mt][nt], 0, 0, 0);
            }
#pragma unroll
            for (int mt = 0; mt < 2; mt++)
                rs[mt] = __builtin_amdgcn_mfma_f32_16x16x32_bf16(
                    pf[mt], ones, rs[mt], 0, 0, 0);
        }
        __builtin_amdgcn_s_setprio(0);
#pragma unroll
        for (int mt = 0; mt < 2; mt++)
#pragma unroll
            for (int r = 0; r < 4; r++) l_i[mt][r] += rs[mt][r];
        __syncthreads();
    }

    int tokb = b * SLEN + q0 + wave * 32 + quad * 4;
#pragma unroll
    for (int mt = 0; mt < 2; mt++) {
#pragma unroll
        for (int r = 0; r < 4; r++) {
            float inv_l = 1.0f / l_i[mt][r];
            int tok = tokb + mt * 16 + r;
#pragma unroll
            for (int nt = 0; nt < 8; nt++) {
                O[(size_t)tok * 2048 + h * 128 + nt * 16 + lane15] =
                    (__bf16)(o_acc[mt][nt][r] * inv_l);
            }
        }
    }
}

// ---------------------------------------------------------------------------
extern "C" void kernel_launch(void* const* d_in, const int* in_sizes, int n_in,
                              void* d_out, int out_size, void* d_ws, size_t ws_size,
                              hipStream_t stream) {
    (void)in_sizes; (void)n_in; (void)out_size; (void)ws_size;
    const int* pos = (const int*)d_in[1];
    float* out = (float*)d_out;

    char* ws = (char*)d_ws;
    size_t off = 0;
    auto alloc = [&](size_t bytes) {
        char* p = ws + off;
        off += (bytes + 255) & ~(size_t)255;
        return p;
    };
    __bf16* x_bf  = (__bf16*)alloc(8388608ull * 2);
    __bf16* Wcat1 = (__bf16*)alloc(4325376ull * 2);  // Wqd | Wkvd | Wkr  (K=2048)
    __bf16* Wcat2 = (__bf16*)alloc(4718592ull * 2);  // Wqu | Wqr        (K=1536)
    __bf16* Wcat3 = (__bf16*)alloc(4194304ull * 2);  // Wku | Wvu        (K=512)
    __bf16* Wob   = (__bf16*)alloc(4194304ull * 2);
    __bf16* c_q   = (__bf16*)alloc(4096ull * 1536 * 2);
    __bf16* c_kv  = (__bf16*)alloc(4096ull * 512 * 2);
    __bf16* v_t   = (__bf16*)alloc(4096ull * 2048 * 2);
    __bf16* q_all = (__bf16*)alloc(4096ull * 3072 * 2);
    __bf16* k_all = (__bf16*)alloc(4096ull * 3072 * 2);
    __bf16* attn_o = (__bf16*)c_q;   // overlays c_q+c_kv (exactly 16.78 MB)

    const float scale_l2 = 1.4426950408889634f / sqrtf(192.0f);
    dim3 blk(256);
    dim3 blk2(512);

    CvArgs cv;
    cv.src[0] = (const float*)d_in[0]; cv.dst[0] = x_bf;
    cv.src[1] = (const float*)d_in[2]; cv.dst[1] = Wcat1;
    cv.src[2] = (const float*)d_in[5]; cv.dst[2] = Wcat1 + 3145728;
    cv.src[3] = (const float*)d_in[8]; cv.dst[3] = Wcat1 + 4194304;
    cv.src[4] = (const float*)d_in[3]; cv.dst[4] = Wcat2;
    cv.src[5] = (const float*)d_in[4]; cv.dst[5] = Wcat2 + 3145728;
    cv.src[6] = (const float*)d_in[6]; cv.dst[6] = Wcat3;
    cv.src[7] = (const float*)d_in[7]; cv.dst[7] = Wcat3 + 1048576;
    cv.src[8] = (const float*)d_in[9]; cv.dst[8] = Wob;
    long ns[9] = {8388608, 3145728, 1048576, 131072, 3145728, 1572864,
                  1048576, 1048576, 4194304};
    cv.cum[0] = 0;
    for (int i = 0; i < 9; i++) cv.cum[i + 1] = cv.cum[i] + ns[i];
    convert_all<<<dim3((unsigned)(cv.cum[9] / 2048)), blk, 0, stream>>>(cv);

    // gemm1a: x @ [Wqd|Wkvd]^T -> c_q | c_kv   (N=2048, K=2048)
    Outs o1 = { c_q, c_kv, nullptr, nullptr };
    gemm_nt2<<<dim3(256), blk2, 0, stream>>>(x_bf, Wcat1, o1, pos, 2048, 2048, 8, 1.0f);
    // gemm1b: k-rope strip (cols 2048..2111) -> k_all[...,128:192] broadcast
    Outs o1b = { nullptr, nullptr, k_all, nullptr };
    gemm_nt<<<dim3(32, 1), blk, 0, stream>>>(x_bf, Wcat1, o1b, pos, 4096, 2112, 2048, 8, 1.0f, 2048);
    // gemm2: c_q @ [Wqu|Wqr]^T -> q_all (nope scatter + rope)  (N=3072, K=1536)
    Outs o2 = { q_all, nullptr, nullptr, nullptr };
    gemm_nt2<<<dim3(384), blk2, 0, stream>>>(c_q, Wcat2, o2, pos, 3072, 1536, 9, scale_l2);
    // gemm3: c_kv @ [Wku|Wvu]^T -> k_all nope + v_t  (N=4096, K=512)
    Outs o3 = { k_all, v_t, nullptr, nullptr };
    gemm_nt2<<<dim3(512), blk2, 0, stream>>>(c_kv, Wcat3, o3, pos, 4096, 512, 10, 1.0f);
    mla_attn<<<dim3(16, 16, 2), blk, 0, stream>>>(q_all, k_all, v_t, attn_o);
    // gemm4: attn_o @ Wo^T -> out fp32  (N=2048, K=2048)
    Outs o4 = { nullptr, nullptr, nullptr, out };
    gemm_nt2<<<dim3(256), blk2, 0, stream>>>(attn_o, Wob, o4, pos, 2048, 2048, 2, 1.0f);
}

// Round 4
// 455.278 us; speedup vs baseline: 1.0529x; 1.0529x over previous
//
#include <hip/hip_runtime.h>
#include <cmath>

#define SLEN 2048

typedef __bf16 bf16x8 __attribute__((ext_vector_type(8)));
typedef float  f32x4  __attribute__((ext_vector_type(4)));

__device__ inline void gld16(const void* g, void* l) {
    __builtin_amdgcn_global_load_lds(
        (const __attribute__((address_space(1))) void*)(uintptr_t)g,
        (__attribute__((address_space(3))) void*)(unsigned)(uintptr_t)l, 16, 0, 0);
}

// ---------------------------------------------------------------------------
// One-launch fp32->bf16 convert of all 9 inputs (segment table by value).
// ---------------------------------------------------------------------------
struct CvArgs {
    const float* src[9];
    __bf16*      dst[9];
    long         cum[10];
};
__global__ __launch_bounds__(256)
void convert_all(CvArgs a) {
    long i8 = ((long)blockIdx.x * 256 + threadIdx.x) * 8;
    if (i8 >= a.cum[9]) return;
    int s = 0;
#pragma unroll
    for (int k = 1; k < 9; k++) if (i8 >= a.cum[k]) s = k;
    long loc = i8 - a.cum[s];
    const float* sp = a.src[s] + loc;
    float4 u0 = *(const float4*)(sp);
    float4 u1 = *(const float4*)(sp + 4);
    bf16x8 o;
    o[0] = (__bf16)u0.x; o[1] = (__bf16)u0.y; o[2] = (__bf16)u0.z; o[3] = (__bf16)u0.w;
    o[4] = (__bf16)u1.x; o[5] = (__bf16)u1.y; o[6] = (__bf16)u1.z; o[7] = (__bf16)u1.w;
    *(bf16x8*)(a.dst[s] + loc) = o;
}

// ---------------------------------------------------------------------------
// NT GEMM, 128x128x64 tiles, 4 waves, global_load_lds + XOR-swizzled LDS.
// v4 changes vs v0 (one variable: sync structure):
//  - double-buffered LDS (2 x 32 KiB = 64 KiB -> still 2 blocks/CU)
//  - stage(t+1) issued BEFORE compute(t); counted s_waitcnt vmcnt(8) + raw
//    s_barrier instead of __syncthreads' vmcnt(0) drain (T4: loads stay in
//    flight across the barrier; staging hides under the 32 MFMAs)
//  - bijective XCD-chunked block remap, m-fastest within chunk (T1): each
//    XCD keeps its B n-panels L2-resident. All grids are multiples of 8.
// Epilogue modes (unchanged from v0):
//  2: fp32 [M,N] row-major (final output)
//  8: down-proj merged: col<1536 -> c_q; col<2048 -> c_kv; tile n0==2048 ->
//     k-rope (rotate pairs i/i+32, broadcast 16 heads into k_all)
//  9: up-Q merged (scaled by `scale`): col<2048 -> q_all nope scatter;
//     col>=2048 -> q-rope into q_all[...,128:192]
// 10: up-KV merged: col<2048 -> k_all nope scatter; col>=2048 -> V transpose
// ---------------------------------------------------------------------------
struct Outs { __bf16* a; __bf16* b; __bf16* c; float* f; };

__global__ __launch_bounds__(256, 2)
void gemm_nt(const __bf16* __restrict__ A, const __bf16* __restrict__ B,
             Outs o, const int* __restrict__ positions,
             int M, int N, int K, int mode, float scale) {
    __shared__ __bf16 As[2][128 * 64];
    __shared__ __bf16 Bs[2][128 * 64];
    int tid = threadIdx.x;
    int wave = tid >> 6, lane = tid & 63;
    int lane15 = lane & 15, quad = lane >> 4;
    int ri = lane >> 3, ci = lane & 7;
    int cg = ci ^ ri;

    // T1: XCD-clustered bijective remap (nwg % 8 == 0 for all our grids),
    // m-fastest within each XCD chunk -> per-XCD B panels stay L2-resident.
    int nwg = gridDim.x * gridDim.y;
    int lin = blockIdx.y * gridDim.x + blockIdx.x;
    int chunk = nwg >> 3;
    int wg = (lin & 7) * chunk + (lin >> 3);
    int m0 = (wg & 31) * 128;                  // gridDim.x == 32 always
    int n0 = (wg >> 5) * 128;

    int wm = (wave & 1) * 64, wn = (wave >> 1) * 64;
    f32x4 acc[4][4] = {};

    auto stage = [&](int k0, int buf) {
#pragma unroll
        for (int t = 0; t < 4; t++) {
            int rr = wave * 32 + t * 8;
            int r = rr + ri;
            gld16(A + (size_t)(m0 + r) * K + k0 + cg * 8, &As[buf][0] + rr * 64);
            int br = n0 + r; if (br > N - 1) br = N - 1;
            gld16(B + (size_t)br * K + k0 + cg * 8, &Bs[buf][0] + rr * 64);
        }
    };

    int NT = K >> 6;
    stage(0, 0);
    for (int t = 0; t < NT; t++) {
        int cur = t & 1;
        if (t + 1 < NT) {
            stage((t + 1) << 6, cur ^ 1);      // 8 loads in flight across barrier
            asm volatile("s_waitcnt vmcnt(8)" ::: "memory");
        } else {
            asm volatile("s_waitcnt vmcnt(0)" ::: "memory");
        }
        __builtin_amdgcn_sched_barrier(0);
        __builtin_amdgcn_s_barrier();          // tile t ready in LDS for all
        __builtin_amdgcn_sched_barrier(0);
#pragma unroll
        for (int kk = 0; kk < 64; kk += 32) {
            int jb = kk >> 3;
            bf16x8 af[4], bfr[4];
#pragma unroll
            for (int mt = 0; mt < 4; mt++) {
                int rA = wm + mt * 16 + lane15;
                af[mt] = *(bf16x8*)(&As[cur][0] + rA * 64 + (((jb + quad) ^ (rA & 7)) << 3));
            }
#pragma unroll
            for (int nt = 0; nt < 4; nt++) {
                int rB = wn + nt * 16 + lane15;
                bfr[nt] = *(bf16x8*)(&Bs[cur][0] + rB * 64 + (((jb + quad) ^ (rB & 7)) << 3));
            }
            __builtin_amdgcn_s_setprio(1);
#pragma unroll
            for (int mt = 0; mt < 4; mt++)
#pragma unroll
                for (int nt = 0; nt < 4; nt++)
                    acc[mt][nt] = __builtin_amdgcn_mfma_f32_16x16x32_bf16(
                        af[mt], bfr[nt], acc[mt][nt], 0, 0, 0);
            __builtin_amdgcn_s_setprio(0);
        }
        __builtin_amdgcn_sched_barrier(0);
        __builtin_amdgcn_s_barrier();          // all reads of buf[cur] done
    }

    const float KLOG = 13.287712379549449f / 32.0f;  // log2(10000)/32

    // --- rope tiles -------------------------------------------------------
    if (mode == 8 && n0 == 2048) {                     // k-rope + broadcast
        if (wn == 0) {
#pragma unroll
            for (int mt = 0; mt < 4; mt++) {
                int row = m0 + wm + mt * 16 + quad * 4;
#pragma unroll
                for (int nt = 0; nt < 2; nt++) {
                    int i = nt * 16 + lane15;          // 0..31
                    float inv = exp2f(-(float)i * KLOG);
#pragma unroll
                    for (int r = 0; r < 4; r++) {
                        int tok = row + r;
                        float p = (float)positions[tok & (SLEN - 1)];
                        float sn, cs; sincosf(p * inv, &sn, &cs);
                        float t1 = acc[mt][nt][r], t2 = acc[mt][nt + 2][r];
                        float rot1 = t1 * cs - t2 * sn;
                        float rot2 = t2 * cs + t1 * sn;
                        size_t ob = (size_t)tok * 3072 + 128;
#pragma unroll
                        for (int hh = 0; hh < 16; hh++) {
                            o.c[ob + hh * 192 + i]      = (__bf16)rot1;
                            o.c[ob + hh * 192 + 32 + i] = (__bf16)rot2;
                        }
                    }
                }
            }
        }
        return;
    }
    if (mode == 9 && n0 >= 2048) {                     // q-rope (scaled)
        int hh = (n0 + wn - 2048) >> 6;
#pragma unroll
        for (int mt = 0; mt < 4; mt++) {
            int row = m0 + wm + mt * 16 + quad * 4;
#pragma unroll
            for (int nt = 0; nt < 2; nt++) {
                int i = nt * 16 + lane15;              // 0..31
                float inv = exp2f(-(float)i * KLOG);
#pragma unroll
                for (int r = 0; r < 4; r++) {
                    int tok = row + r;
                    float p = (float)positions[tok & (SLEN - 1)];
                    float sn, cs; sincosf(p * inv, &sn, &cs);
                    float t1 = acc[mt][nt][r], t2 = acc[mt][nt + 2][r];
                    size_t ob = (size_t)tok * 3072 + hh * 192 + 128;
                    o.a[ob + i]      = (__bf16)((t1 * cs - t2 * sn) * scale);
                    o.a[ob + 32 + i] = (__bf16)((t2 * cs + t1 * sn) * scale);
                }
            }
        }
        return;
    }

    // --- generic epilogues ------------------------------------------------
#pragma unroll
    for (int mt = 0; mt < 4; mt++) {
        int row = m0 + wm + mt * 16 + quad * 4;
#pragma unroll
        for (int nt = 0; nt < 4; nt++) {
            int col = n0 + wn + nt * 16 + lane15;
            if (col < N) {
#pragma unroll
                for (int r = 0; r < 4; r++) {
                    float v = acc[mt][nt][r];
                    size_t rw = (size_t)(row + r);
                    if (mode == 2) {
                        o.f[rw * N + col] = v;
                    } else if (mode == 8) {
                        if (col < 1536) o.a[rw * 1536 + col] = (__bf16)v;
                        else            o.b[rw * 512 + col - 1536] = (__bf16)v;
                    } else if (mode == 9) {
                        o.a[rw * 3072 + (col >> 7) * 192 + (col & 127)] =
                            (__bf16)(v * scale);
                    } else {  // 10
                        if (col < 2048)
                            o.a[rw * 3072 + (col >> 7) * 192 + (col & 127)] = (__bf16)v;
                        else {
                            int d = col - 2048;
                            o.b[((size_t)d * 2 + (rw >> 11)) * 2048 + (rw & 2047)] = (__bf16)v;
                        }
                    }
                }
            }
        }
    }
}

// ---------------------------------------------------------------------------
// Causal flash attention, Q-tile 128 (4 waves x 32 q-rows), K/V-tile 64.
// v0 structure (complementary (qt,15-qt) b-partners -> every CU's co-resident
// pair totals 17 tile-units) + s_setprio(1) around MFMA clusters (T5).
// Measured 100.4 us in round 3.
// ---------------------------------------------------------------------------
__global__ __launch_bounds__(256, 2)
void mla_attn(const __bf16* __restrict__ Q, const __bf16* __restrict__ K,
              const __bf16* __restrict__ Vt, __bf16* __restrict__ O) {
    __shared__ __bf16 Ks[64 * 192];
    __shared__ __bf16 Vs[128 * 64];
    __shared__ __bf16 Ps[4][32][72];
    int tid = threadIdx.x, wave = tid >> 6, lane = tid & 63;
    int lane15 = lane & 15, quad = lane >> 4;
    int h = blockIdx.y, b = blockIdx.z;
    int x = blockIdx.x;
    int qt0 = (x & 1) ? (x >> 1) : (15 - (x >> 1));
    int qt = b ? (15 - qt0) : qt0;
    int q0 = qt * 128;
    const __bf16* Qb  = Q + (size_t)b * SLEN * 3072 + h * 192;
    const __bf16* Kb  = K + (size_t)b * SLEN * 3072 + h * 192;
    const __bf16* vtb = Vt + ((size_t)(h * 128) * 2 + b) * 2048;

    bf16x8 qf[2][6];
#pragma unroll
    for (int mt = 0; mt < 2; mt++) {
        int qrow = q0 + wave * 32 + mt * 16 + lane15;
#pragma unroll
        for (int kk = 0; kk < 6; kk++)
            qf[mt][kk] = *(const bf16x8*)(Qb + (size_t)qrow * 3072 + kk * 32 + quad * 8);
    }
    bf16x8 ones;
#pragma unroll
    for (int e = 0; e < 8; e++) ones[e] = (__bf16)1.0f;

    f32x4 o_acc[2][8] = {};
    float m_i[2][4], l_i[2][4];
#pragma unroll
    for (int mt = 0; mt < 2; mt++)
#pragma unroll
        for (int r = 0; r < 4; r++) { m_i[mt][r] = -3.0e38f; l_i[mt][r] = 0.0f; }

    for (int j0 = 0; j0 <= q0 + 64; j0 += 64) {
        // stage K (64x192) and V (128x64), swizzled, via global_load_lds
#pragma unroll
        for (int t = 0; t < 6; t++) {
            int sb = (wave * 6 + t) * 64;
            int slot = sb + lane;
            int r = slot / 24;
            int c = slot - r * 24;
            int cgk = (c & ~7) | ((c & 7) ^ (r & 7));
            gld16(Kb + (size_t)(j0 + r) * 3072 + cgk * 8, Ks + sb * 8);
        }
#pragma unroll
        for (int t = 0; t < 4; t++) {
            int sb = (wave * 4 + t) * 64;
            int slot = sb + lane;
            int r = slot >> 3, c = slot & 7;
            gld16(vtb + (size_t)r * 4096 + j0 + (c ^ (r & 7)) * 8, Vs + sb * 8);
        }
        __syncthreads();

        // QK^T: 2 m-tiles x 4 n-tiles
        f32x4 acc[2][4] = {};
        __builtin_amdgcn_s_setprio(1);
#pragma unroll
        for (int kk = 0; kk < 6; kk++) {
#pragma unroll
            for (int nt = 0; nt < 4; nt++) {
                int n = nt * 16 + lane15;
                int j = kk * 4 + quad;
                int cl = (j & ~7) | ((j & 7) ^ (n & 7));
                bf16x8 kf = *(bf16x8*)(Ks + n * 192 + cl * 8);
#pragma unroll
                for (int mt = 0; mt < 2; mt++)
                    acc[mt][nt] = __builtin_amdgcn_mfma_f32_16x16x32_bf16(
                        qf[mt][kk], kf, acc[mt][nt], 0, 0, 0);
            }
        }
        __builtin_amdgcn_s_setprio(0);

        if (j0 >= q0) {  // causal mask (only last two tiles)
#pragma unroll
            for (int mt = 0; mt < 2; mt++) {
                int rowg = q0 + wave * 32 + mt * 16 + quad * 4;
#pragma unroll
                for (int nt = 0; nt < 4; nt++) {
                    int colg = j0 + nt * 16 + lane15;
#pragma unroll
                    for (int r = 0; r < 4; r++)
                        if (colg > rowg + r) acc[mt][nt][r] = -3.0e38f;
                }
            }
        }

        // threshold-max: slow path only when tile max exceeds m+24
        float mx[2][4];
        bool need = false;
#pragma unroll
        for (int mt = 0; mt < 2; mt++)
#pragma unroll
            for (int r = 0; r < 4; r++) {
                float v = fmaxf(fmaxf(acc[mt][0][r], acc[mt][1][r]),
                                fmaxf(acc[mt][2][r], acc[mt][3][r]));
                mx[mt][r] = v;
                need = need || (v > m_i[mt][r] + 24.0f);
            }
        if (__any(need)) {
#pragma unroll
            for (int mt = 0; mt < 2; mt++)
#pragma unroll
                for (int r = 0; r < 4; r++) {
                    float v = mx[mt][r];
#pragma unroll
                    for (int d = 8; d >= 1; d >>= 1) v = fmaxf(v, __shfl_xor(v, d));
                    float mn = fmaxf(m_i[mt][r], v);
                    float alpha = exp2f(m_i[mt][r] - mn);
                    m_i[mt][r] = mn;
                    l_i[mt][r] *= alpha;
#pragma unroll
                    for (int nt = 0; nt < 8; nt++) o_acc[mt][nt][r] *= alpha;
                }
        }

        // P = exp2(acc - m), store to Ps (A-layout round-trip)
#pragma unroll
        for (int mt = 0; mt < 2; mt++)
#pragma unroll
            for (int r = 0; r < 4; r++)
#pragma unroll
                for (int nt = 0; nt < 4; nt++) {
                    float pp = exp2f(acc[mt][nt][r] - m_i[mt][r]);
                    Ps[wave][mt * 16 + quad * 4 + r][nt * 16 + lane15] = (__bf16)pp;
                }

        // PV + row-sum MFMA
        f32x4 rs[2] = {};
        __builtin_amdgcn_s_setprio(1);
#pragma unroll
        for (int ks = 0; ks < 2; ks++) {
            bf16x8 pf[2];
#pragma unroll
            for (int mt = 0; mt < 2; mt++)
                pf[mt] = *(bf16x8*)(&Ps[wave][mt * 16 + lane15][ks * 32 + quad * 8]);
#pragma unroll
            for (int nt = 0; nt < 8; nt++) {
                int nn = nt * 16 + lane15;
                int j = ks * 4 + quad;
                bf16x8 vf = *(bf16x8*)(Vs + nn * 64 + (j ^ (nn & 7)) * 8);
#pragma unroll
                for (int mt = 0; mt < 2; mt++)
                    o_acc[mt][nt] = __builtin_amdgcn_mfma_f32_16x16x32_bf16(
                        pf[mt], vf, o_acc[mt][nt], 0, 0, 0);
            }
#pragma unroll
            for (int mt = 0; mt < 2; mt++)
                rs[mt] = __builtin_amdgcn_mfma_f32_16x16x32_bf16(
                    pf[mt], ones, rs[mt], 0, 0, 0);
        }
        __builtin_amdgcn_s_setprio(0);
#pragma unroll
        for (int mt = 0; mt < 2; mt++)
#pragma unroll
            for (int r = 0; r < 4; r++) l_i[mt][r] += rs[mt][r];
        __syncthreads();
    }

    int tokb = b * SLEN + q0 + wave * 32 + quad * 4;
#pragma unroll
    for (int mt = 0; mt < 2; mt++) {
#pragma unroll
        for (int r = 0; r < 4; r++) {
            float inv_l = 1.0f / l_i[mt][r];
            int tok = tokb + mt * 16 + r;
#pragma unroll
            for (int nt = 0; nt < 8; nt++) {
                O[(size_t)tok * 2048 + h * 128 + nt * 16 + lane15] =
                    (__bf16)(o_acc[mt][nt][r] * inv_l);
            }
        }
    }
}

// ---------------------------------------------------------------------------
extern "C" void kernel_launch(void* const* d_in, const int* in_sizes, int n_in,
                              void* d_out, int out_size, void* d_ws, size_t ws_size,
                              hipStream_t stream) {
    (void)in_sizes; (void)n_in; (void)out_size; (void)ws_size;
    const int* pos = (const int*)d_in[1];
    float* out = (float*)d_out;

    char* ws = (char*)d_ws;
    size_t off = 0;
    auto alloc = [&](size_t bytes) {
        char* p = ws + off;
        off += (bytes + 255) & ~(size_t)255;
        return p;
    };
    __bf16* x_bf  = (__bf16*)alloc(8388608ull * 2);
    __bf16* Wcat1 = (__bf16*)alloc(4325376ull * 2);  // Wqd | Wkvd | Wkr  (K=2048)
    __bf16* Wcat2 = (__bf16*)alloc(4718592ull * 2);  // Wqu | Wqr        (K=1536)
    __bf16* Wcat3 = (__bf16*)alloc(4194304ull * 2);  // Wku | Wvu        (K=512)
    __bf16* Wob   = (__bf16*)alloc(4194304ull * 2);
    __bf16* c_q   = (__bf16*)alloc(4096ull * 1536 * 2);
    __bf16* c_kv  = (__bf16*)alloc(4096ull * 512 * 2);
    __bf16* v_t   = (__bf16*)alloc(4096ull * 2048 * 2);
    __bf16* q_all = (__bf16*)alloc(4096ull * 3072 * 2);
    __bf16* k_all = (__bf16*)alloc(4096ull * 3072 * 2);
    __bf16* attn_o = (__bf16*)c_q;   // overlays c_q+c_kv (exactly 16.78 MB)

    const float scale_l2 = 1.4426950408889634f / sqrtf(192.0f);
    dim3 blk(256);

    CvArgs cv;
    cv.src[0] = (const float*)d_in[0]; cv.dst[0] = x_bf;
    cv.src[1] = (const float*)d_in[2]; cv.dst[1] = Wcat1;
    cv.src[2] = (const float*)d_in[5]; cv.dst[2] = Wcat1 + 3145728;
    cv.src[3] = (const float*)d_in[8]; cv.dst[3] = Wcat1 + 4194304;
    cv.src[4] = (const float*)d_in[3]; cv.dst[4] = Wcat2;
    cv.src[5] = (const float*)d_in[4]; cv.dst[5] = Wcat2 + 3145728;
    cv.src[6] = (const float*)d_in[6]; cv.dst[6] = Wcat3;
    cv.src[7] = (const float*)d_in[7]; cv.dst[7] = Wcat3 + 1048576;
    cv.src[8] = (const float*)d_in[9]; cv.dst[8] = Wob;
    long ns[9] = {8388608, 3145728, 1048576, 131072, 3145728, 1572864,
                  1048576, 1048576, 4194304};
    cv.cum[0] = 0;
    for (int i = 0; i < 9; i++) cv.cum[i + 1] = cv.cum[i] + ns[i];
    convert_all<<<dim3((unsigned)(cv.cum[9] / 2048)), blk, 0, stream>>>(cv);

    Outs o1 = { c_q, c_kv, k_all, nullptr };
    gemm_nt<<<dim3(32, 17), blk, 0, stream>>>(x_bf, Wcat1, o1, pos, 4096, 2112, 2048, 8, 1.0f);
    Outs o2 = { q_all, nullptr, nullptr, nullptr };
    gemm_nt<<<dim3(32, 24), blk, 0, stream>>>(c_q, Wcat2, o2, pos, 4096, 3072, 1536, 9, scale_l2);
    Outs o3 = { k_all, v_t, nullptr, nullptr };
    gemm_nt<<<dim3(32, 32), blk, 0, stream>>>(c_kv, Wcat3, o3, pos, 4096, 4096, 512, 10, 1.0f);
    mla_attn<<<dim3(16, 16, 2), blk, 0, stream>>>(q_all, k_all, v_t, attn_o);
    Outs o4 = { nullptr, nullptr, nullptr, out };
    gemm_nt<<<dim3(32, 16), blk, 0, stream>>>(attn_o, Wob, o4, pos, 4096, 2048, 2048, 2, 1.0f);
}

// Round 5
// 417.109 us; speedup vs baseline: 1.1493x; 1.0915x over previous
//
#include <hip/hip_runtime.h>
#include <cmath>

#define SLEN 2048

typedef __bf16 bf16x8 __attribute__((ext_vector_type(8)));
typedef float  f32x4  __attribute__((ext_vector_type(4)));

__device__ inline void gld16(const void* g, void* l) {
    __builtin_amdgcn_global_load_lds(
        (const __attribute__((address_space(1))) void*)(uintptr_t)g,
        (__attribute__((address_space(3))) void*)(unsigned)(uintptr_t)l, 16, 0, 0);
}

// ---------------------------------------------------------------------------
// One-launch fp32->bf16 convert of all 9 inputs (segment table by value).
// ---------------------------------------------------------------------------
struct CvArgs {
    const float* src[9];
    __bf16*      dst[9];
    long         cum[10];
};
__global__ __launch_bounds__(256)
void convert_all(CvArgs a) {
    long i8 = ((long)blockIdx.x * 256 + threadIdx.x) * 8;
    if (i8 >= a.cum[9]) return;
    int s = 0;
#pragma unroll
    for (int k = 1; k < 9; k++) if (i8 >= a.cum[k]) s = k;
    long loc = i8 - a.cum[s];
    const float* sp = a.src[s] + loc;
    float4 u0 = *(const float4*)(sp);
    float4 u1 = *(const float4*)(sp + 4);
    bf16x8 o;
    o[0] = (__bf16)u0.x; o[1] = (__bf16)u0.y; o[2] = (__bf16)u0.z; o[3] = (__bf16)u0.w;
    o[4] = (__bf16)u1.x; o[5] = (__bf16)u1.y; o[6] = (__bf16)u1.z; o[7] = (__bf16)u1.w;
    *(bf16x8*)(a.dst[s] + loc) = o;
}

// ---------------------------------------------------------------------------
// NT GEMM, 128x128x64 tiles, 4 waves, global_load_lds + XOR-swizzled LDS.
// v0 structure exactly (single-buffer, __syncthreads) — the proven-best
// 2-phase config.  One change: __launch_bounds__(256,3) so the register
// allocator caps at ~168 VGPR -> 3 blocks/CU (m97's occupancy; m114's
// cross-block overlap is what hides the end-of-tile barrier drain).
// Epilogue modes:
//  2: fp32 [M,N] row-major (final output)
//  8: down-proj merged: col<1536 -> c_q; col<2048 -> c_kv; tile n0==2048 ->
//     k-rope (rotate pairs i/i+32, broadcast 16 heads into k_all)
//  9: up-Q merged (scaled by `scale`): col<2048 -> q_all nope scatter;
//     col>=2048 -> q-rope into q_all[...,128:192]
// 10: up-KV merged: col<2048 -> k_all nope scatter; col>=2048 -> V transpose
// ---------------------------------------------------------------------------
struct Outs { __bf16* a; __bf16* b; __bf16* c; float* f; };

__global__ __launch_bounds__(256, 3)
void gemm_nt(const __bf16* __restrict__ A, const __bf16* __restrict__ B,
             Outs o, const int* __restrict__ positions,
             int M, int N, int K, int mode, float scale) {
    __shared__ __bf16 As[128 * 64];
    __shared__ __bf16 Bs[128 * 64];
    int tid = threadIdx.x;
    int wave = tid >> 6, lane = tid & 63;
    int lane15 = lane & 15, quad = lane >> 4;
    int ri = lane >> 3, ci = lane & 7;
    int cg = ci ^ ri;
    int m0 = blockIdx.x * 128, n0 = blockIdx.y * 128;
    int wm = (wave & 1) * 64, wn = (wave >> 1) * 64;
    f32x4 acc[4][4] = {};

    for (int k0 = 0; k0 < K; k0 += 64) {
#pragma unroll
        for (int t = 0; t < 4; t++) {
            int rr = wave * 32 + t * 8;
            int r = rr + ri;
            gld16(A + (size_t)(m0 + r) * K + k0 + cg * 8, As + rr * 64);
            int br = n0 + r; if (br > N - 1) br = N - 1;
            gld16(B + (size_t)br * K + k0 + cg * 8, Bs + rr * 64);
        }
        __syncthreads();
#pragma unroll
        for (int kk = 0; kk < 64; kk += 32) {
            int jb = kk >> 3;
            bf16x8 af[4], bfr[4];
#pragma unroll
            for (int mt = 0; mt < 4; mt++) {
                int rA = wm + mt * 16 + lane15;
                af[mt] = *(bf16x8*)(As + rA * 64 + (((jb + quad) ^ (rA & 7)) << 3));
            }
#pragma unroll
            for (int nt = 0; nt < 4; nt++) {
                int rB = wn + nt * 16 + lane15;
                bfr[nt] = *(bf16x8*)(Bs + rB * 64 + (((jb + quad) ^ (rB & 7)) << 3));
            }
#pragma unroll
            for (int mt = 0; mt < 4; mt++)
#pragma unroll
                for (int nt = 0; nt < 4; nt++)
                    acc[mt][nt] = __builtin_amdgcn_mfma_f32_16x16x32_bf16(
                        af[mt], bfr[nt], acc[mt][nt], 0, 0, 0);
        }
        __syncthreads();
    }

    const float KLOG = 13.287712379549449f / 32.0f;  // log2(10000)/32

    // --- rope tiles -------------------------------------------------------
    if (mode == 8 && n0 == 2048) {                     // k-rope + broadcast
        if (wn == 0) {
#pragma unroll
            for (int mt = 0; mt < 4; mt++) {
                int row = m0 + wm + mt * 16 + quad * 4;
#pragma unroll
                for (int nt = 0; nt < 2; nt++) {
                    int i = nt * 16 + lane15;          // 0..31
                    float inv = exp2f(-(float)i * KLOG);
#pragma unroll
                    for (int r = 0; r < 4; r++) {
                        int tok = row + r;
                        float p = (float)positions[tok & (SLEN - 1)];
                        float sn, cs; sincosf(p * inv, &sn, &cs);
                        float t1 = acc[mt][nt][r], t2 = acc[mt][nt + 2][r];
                        float rot1 = t1 * cs - t2 * sn;
                        float rot2 = t2 * cs + t1 * sn;
                        size_t ob = (size_t)tok * 3072 + 128;
#pragma unroll
                        for (int hh = 0; hh < 16; hh++) {
                            o.c[ob + hh * 192 + i]      = (__bf16)rot1;
                            o.c[ob + hh * 192 + 32 + i] = (__bf16)rot2;
                        }
                    }
                }
            }
        }
        return;
    }
    if (mode == 9 && n0 >= 2048) {                     // q-rope (scaled)
        int hh = (n0 + wn - 2048) >> 6;
#pragma unroll
        for (int mt = 0; mt < 4; mt++) {
            int row = m0 + wm + mt * 16 + quad * 4;
#pragma unroll
            for (int nt = 0; nt < 2; nt++) {
                int i = nt * 16 + lane15;              // 0..31
                float inv = exp2f(-(float)i * KLOG);
#pragma unroll
                for (int r = 0; r < 4; r++) {
                    int tok = row + r;
                    float p = (float)positions[tok & (SLEN - 1)];
                    float sn, cs; sincosf(p * inv, &sn, &cs);
                    float t1 = acc[mt][nt][r], t2 = acc[mt][nt + 2][r];
                    size_t ob = (size_t)tok * 3072 + hh * 192 + 128;
                    o.a[ob + i]      = (__bf16)((t1 * cs - t2 * sn) * scale);
                    o.a[ob + 32 + i] = (__bf16)((t2 * cs + t1 * sn) * scale);
                }
            }
        }
        return;
    }

    // --- generic epilogues ------------------------------------------------
#pragma unroll
    for (int mt = 0; mt < 4; mt++) {
        int row = m0 + wm + mt * 16 + quad * 4;
#pragma unroll
        for (int nt = 0; nt < 4; nt++) {
            int col = n0 + wn + nt * 16 + lane15;
            if (col < N) {
#pragma unroll
                for (int r = 0; r < 4; r++) {
                    float v = acc[mt][nt][r];
                    size_t rw = (size_t)(row + r);
                    if (mode == 2) {
                        o.f[rw * N + col] = v;
                    } else if (mode == 8) {
                        if (col < 1536) o.a[rw * 1536 + col] = (__bf16)v;
                        else            o.b[rw * 512 + col - 1536] = (__bf16)v;
                    } else if (mode == 9) {
                        o.a[rw * 3072 + (col >> 7) * 192 + (col & 127)] =
                            (__bf16)(v * scale);
                    } else {  // 10
                        if (col < 2048)
                            o.a[rw * 3072 + (col >> 7) * 192 + (col & 127)] = (__bf16)v;
                        else {
                            int d = col - 2048;
                            o.b[((size_t)d * 2 + (rw >> 11)) * 2048 + (rw & 2047)] = (__bf16)v;
                        }
                    }
                }
            }
        }
    }
}

// ---------------------------------------------------------------------------
// Causal flash attention, Q-tile 128 (4 waves x 32 q-rows), K/V-tile 64.
// v0 structure + setprio (r3: neutral/+1%), plus T1 XCD grouping:
// remap block ids so all 16 q-tile blocks of a (b,h) land on ONE XCD
// (id%8 -> XCD per m09/HK).  K+V per (b,h) = 1.3 MB -> L2-resident re-reads.
// Partner blocks (lin, lin+256) keep (h,x) and flip b, so v0's complementary
// (qt,15-qt) per-CU balance is preserved exactly.
// ---------------------------------------------------------------------------
__global__ __launch_bounds__(256, 2)
void mla_attn(const __bf16* __restrict__ Q, const __bf16* __restrict__ K,
              const __bf16* __restrict__ Vt, __bf16* __restrict__ O) {
    __shared__ __bf16 Ks[64 * 192];
    __shared__ __bf16 Vs[128 * 64];
    __shared__ __bf16 Ps[4][32][72];
    int tid = threadIdx.x, wave = tid >> 6, lane = tid & 63;
    int lane15 = lane & 15, quad = lane >> 4;

    // T1 remap: lin -> (xcd, slot); group g = (b,h) = xcd + 8*(slot>>4);
    // member x = slot & 15.  All members of g share lin%8 == g&7 -> same XCD.
    int lin = blockIdx.x + (blockIdx.y << 4) + (blockIdx.z << 8);
    int xcd = lin & 7, slot = lin >> 3;
    int x = slot & 15;
    int g = xcd + ((slot >> 4) << 3);
    int h = g & 15, b = g >> 4;

    int qt0 = (x & 1) ? (x >> 1) : (15 - (x >> 1));
    int qt = b ? (15 - qt0) : qt0;
    int q0 = qt * 128;
    const __bf16* Qb  = Q + (size_t)b * SLEN * 3072 + h * 192;
    const __bf16* Kb  = K + (size_t)b * SLEN * 3072 + h * 192;
    const __bf16* vtb = Vt + ((size_t)(h * 128) * 2 + b) * 2048;

    bf16x8 qf[2][6];
#pragma unroll
    for (int mt = 0; mt < 2; mt++) {
        int qrow = q0 + wave * 32 + mt * 16 + lane15;
#pragma unroll
        for (int kk = 0; kk < 6; kk++)
            qf[mt][kk] = *(const bf16x8*)(Qb + (size_t)qrow * 3072 + kk * 32 + quad * 8);
    }
    bf16x8 ones;
#pragma unroll
    for (int e = 0; e < 8; e++) ones[e] = (__bf16)1.0f;

    f32x4 o_acc[2][8] = {};
    float m_i[2][4], l_i[2][4];
#pragma unroll
    for (int mt = 0; mt < 2; mt++)
#pragma unroll
        for (int r = 0; r < 4; r++) { m_i[mt][r] = -3.0e38f; l_i[mt][r] = 0.0f; }

    for (int j0 = 0; j0 <= q0 + 64; j0 += 64) {
        // stage K (64x192) and V (128x64), swizzled, via global_load_lds
#pragma unroll
        for (int t = 0; t < 6; t++) {
            int sb = (wave * 6 + t) * 64;
            int slot2 = sb + lane;
            int r = slot2 / 24;
            int c = slot2 - r * 24;
            int cgk = (c & ~7) | ((c & 7) ^ (r & 7));
            gld16(Kb + (size_t)(j0 + r) * 3072 + cgk * 8, Ks + sb * 8);
        }
#pragma unroll
        for (int t = 0; t < 4; t++) {
            int sb = (wave * 4 + t) * 64;
            int slot2 = sb + lane;
            int r = slot2 >> 3, c = slot2 & 7;
            gld16(vtb + (size_t)r * 4096 + j0 + (c ^ (r & 7)) * 8, Vs + sb * 8);
        }
        __syncthreads();

        // QK^T: 2 m-tiles x 4 n-tiles
        f32x4 acc[2][4] = {};
        __builtin_amdgcn_s_setprio(1);
#pragma unroll
        for (int kk = 0; kk < 6; kk++) {
#pragma unroll
            for (int nt = 0; nt < 4; nt++) {
                int n = nt * 16 + lane15;
                int j = kk * 4 + quad;
                int cl = (j & ~7) | ((j & 7) ^ (n & 7));
                bf16x8 kf = *(bf16x8*)(Ks + n * 192 + cl * 8);
#pragma unroll
                for (int mt = 0; mt < 2; mt++)
                    acc[mt][nt] = __builtin_amdgcn_mfma_f32_16x16x32_bf16(
                        qf[mt][kk], kf, acc[mt][nt], 0, 0, 0);
            }
        }
        __builtin_amdgcn_s_setprio(0);

        if (j0 >= q0) {  // causal mask (only last two tiles)
#pragma unroll
            for (int mt = 0; mt < 2; mt++) {
                int rowg = q0 + wave * 32 + mt * 16 + quad * 4;
#pragma unroll
                for (int nt = 0; nt < 4; nt++) {
                    int colg = j0 + nt * 16 + lane15;
#pragma unroll
                    for (int r = 0; r < 4; r++)
                        if (colg > rowg + r) acc[mt][nt][r] = -3.0e38f;
                }
            }
        }

        // threshold-max: slow path only when tile max exceeds m+24
        float mx[2][4];
        bool need = false;
#pragma unroll
        for (int mt = 0; mt < 2; mt++)
#pragma unroll
            for (int r = 0; r < 4; r++) {
                float v = fmaxf(fmaxf(acc[mt][0][r], acc[mt][1][r]),
                                fmaxf(acc[mt][2][r], acc[mt][3][r]));
                mx[mt][r] = v;
                need = need || (v > m_i[mt][r] + 24.0f);
            }
        if (__any(need)) {
#pragma unroll
            for (int mt = 0; mt < 2; mt++)
#pragma unroll
                for (int r = 0; r < 4; r++) {
                    float v = mx[mt][r];
#pragma unroll
                    for (int d = 8; d >= 1; d >>= 1) v = fmaxf(v, __shfl_xor(v, d));
                    float mn = fmaxf(m_i[mt][r], v);
                    float alpha = exp2f(m_i[mt][r] - mn);
                    m_i[mt][r] = mn;
                    l_i[mt][r] *= alpha;
#pragma unroll
                    for (int nt = 0; nt < 8; nt++) o_acc[mt][nt][r] *= alpha;
                }
        }

        // P = exp2(acc - m), store to Ps (A-layout round-trip)
#pragma unroll
        for (int mt = 0; mt < 2; mt++)
#pragma unroll
            for (int r = 0; r < 4; r++)
#pragma unroll
                for (int nt = 0; nt < 4; nt++) {
                    float pp = exp2f(acc[mt][nt][r] - m_i[mt][r]);
                    Ps[wave][mt * 16 + quad * 4 + r][nt * 16 + lane15] = (__bf16)pp;
                }

        // PV + row-sum MFMA
        f32x4 rs[2] = {};
        __builtin_amdgcn_s_setprio(1);
#pragma unroll
        for (int ks = 0; ks < 2; ks++) {
            bf16x8 pf[2];
#pragma unroll
            for (int mt = 0; mt < 2; mt++)
                pf[mt] = *(bf16x8*)(&Ps[wave][mt * 16 + lane15][ks * 32 + quad * 8]);
#pragma unroll
            for (int nt = 0; nt < 8; nt++) {
                int nn = nt * 16 + lane15;
                int j = ks * 4 + quad;
                bf16x8 vf = *(bf16x8*)(Vs + nn * 64 + (j ^ (nn & 7)) * 8);
#pragma unroll
                for (int mt = 0; mt < 2; mt++)
                    o_acc[mt][nt] = __builtin_amdgcn_mfma_f32_16x16x32_bf16(
                        pf[mt], vf, o_acc[mt][nt], 0, 0, 0);
            }
#pragma unroll
            for (int mt = 0; mt < 2; mt++)
                rs[mt] = __builtin_amdgcn_mfma_f32_16x16x32_bf16(
                    pf[mt], ones, rs[mt], 0, 0, 0);
        }
        __builtin_amdgcn_s_setprio(0);
#pragma unroll
        for (int mt = 0; mt < 2; mt++)
#pragma unroll
            for (int r = 0; r < 4; r++) l_i[mt][r] += rs[mt][r];
        __syncthreads();
    }

    int tokb = b * SLEN + q0 + wave * 32 + quad * 4;
#pragma unroll
    for (int mt = 0; mt < 2; mt++) {
#pragma unroll
        for (int r = 0; r < 4; r++) {
            float inv_l = 1.0f / l_i[mt][r];
            int tok = tokb + mt * 16 + r;
#pragma unroll
            for (int nt = 0; nt < 8; nt++) {
                O[(size_t)tok * 2048 + h * 128 + nt * 16 + lane15] =
                    (__bf16)(o_acc[mt][nt][r] * inv_l);
            }
        }
    }
}

// ---------------------------------------------------------------------------
extern "C" void kernel_launch(void* const* d_in, const int* in_sizes, int n_in,
                              void* d_out, int out_size, void* d_ws, size_t ws_size,
                              hipStream_t stream) {
    (void)in_sizes; (void)n_in; (void)out_size; (void)ws_size;
    const int* pos = (const int*)d_in[1];
    float* out = (float*)d_out;

    char* ws = (char*)d_ws;
    size_t off = 0;
    auto alloc = [&](size_t bytes) {
        char* p = ws + off;
        off += (bytes + 255) & ~(size_t)255;
        return p;
    };
    __bf16* x_bf  = (__bf16*)alloc(8388608ull * 2);
    __bf16* Wcat1 = (__bf16*)alloc(4325376ull * 2);  // Wqd | Wkvd | Wkr  (K=2048)
    __bf16* Wcat2 = (__bf16*)alloc(4718592ull * 2);  // Wqu | Wqr        (K=1536)
    __bf16* Wcat3 = (__bf16*)alloc(4194304ull * 2);  // Wku | Wvu        (K=512)
    __bf16* Wob   = (__bf16*)alloc(4194304ull * 2);
    __bf16* c_q   = (__bf16*)alloc(4096ull * 1536 * 2);
    __bf16* c_kv  = (__bf16*)alloc(4096ull * 512 * 2);
    __bf16* v_t   = (__bf16*)alloc(4096ull * 2048 * 2);
    __bf16* q_all = (__bf16*)alloc(4096ull * 3072 * 2);
    __bf16* k_all = (__bf16*)alloc(4096ull * 3072 * 2);
    __bf16* attn_o = (__bf16*)c_q;   // overlays c_q+c_kv (exactly 16.78 MB)

    const float scale_l2 = 1.4426950408889634f / sqrtf(192.0f);
    dim3 blk(256);

    CvArgs cv;
    cv.src[0] = (const float*)d_in[0]; cv.dst[0] = x_bf;
    cv.src[1] = (const float*)d_in[2]; cv.dst[1] = Wcat1;
    cv.src[2] = (const float*)d_in[5]; cv.dst[2] = Wcat1 + 3145728;
    cv.src[3] = (const float*)d_in[8]; cv.dst[3] = Wcat1 + 4194304;
    cv.src[4] = (const float*)d_in[3]; cv.dst[4] = Wcat2;
    cv.src[5] = (const float*)d_in[4]; cv.dst[5] = Wcat2 + 3145728;
    cv.src[6] = (const float*)d_in[6]; cv.dst[6] = Wcat3;
    cv.src[7] = (const float*)d_in[7]; cv.dst[7] = Wcat3 + 1048576;
    cv.src[8] = (const float*)d_in[9]; cv.dst[8] = Wob;
    long ns[9] = {8388608, 3145728, 1048576, 131072, 3145728, 1572864,
                  1048576, 1048576, 4194304};
    cv.cum[0] = 0;
    for (int i = 0; i < 9; i++) cv.cum[i + 1] = cv.cum[i] + ns[i];
    convert_all<<<dim3((unsigned)(cv.cum[9] / 2048)), blk, 0, stream>>>(cv);

    Outs o1 = { c_q, c_kv, k_all, nullptr };
    gemm_nt<<<dim3(32, 17), blk, 0, stream>>>(x_bf, Wcat1, o1, pos, 4096, 2112, 2048, 8, 1.0f);
    Outs o2 = { q_all, nullptr, nullptr, nullptr };
    gemm_nt<<<dim3(32, 24), blk, 0, stream>>>(c_q, Wcat2, o2, pos, 4096, 3072, 1536, 9, scale_l2);
    Outs o3 = { k_all, v_t, nullptr, nullptr };
    gemm_nt<<<dim3(32, 32), blk, 0, stream>>>(c_kv, Wcat3, o3, pos, 4096, 4096, 512, 10, 1.0f);
    mla_attn<<<dim3(16, 16, 2), blk, 0, stream>>>(q_all, k_all, v_t, attn_o);
    Outs o4 = { nullptr, nullptr, nullptr, out };
    gemm_nt<<<dim3(32, 16), blk, 0, stream>>>(attn_o, Wob, o4, pos, 4096, 2048, 2048, 2, 1.0f);
}